// Round 3
// baseline (35664.966 us; speedup 1.0000x reference)
//
#include <hip/hip_runtime.h>
#include <math.h>

// Problem constants
#define BB 256
#define NN 32
#define HH 256
#define FF 7
#define TT 496            // N*(N-1)/2

// Workspace layout (floats)
// WREG: per-thread register-load layout: float4 quad q of thread t at [(q*1024+t)*4]
//       thread t: half=t>>9 (k in [128*half,128*half+128)), m=t&511,
//       outputs {m, m+512, m+1024}; quad q: col c=q>>5, kq=q&31
#define WS_WREG  0          // 393216 floats
#define WS_WTG   393216     // [256][1536] k-major graph weights (o = [gi(768)|gh(768)])
#define WS_ABN   786432     // A[7][768] (Wih_node[:,c]+bih) then B[7][768] (Wih_node[:,7+c])
#define WS_WS1T  797184     // [256][64]  Ws1 transposed
#define WS_PROBS 813568     // [256][496]
#define PREP_TOTAL 813568

__global__ void prep_kernel(const float* __restrict__ Wih_node,
                            const float* __restrict__ Whh_node,
                            const float* __restrict__ bih_node,
                            const float* __restrict__ Wih_graph,
                            const float* __restrict__ Whh_graph,
                            const float* __restrict__ Ws1,
                            float* __restrict__ ws) {
  int idx = blockIdx.x * blockDim.x + threadIdx.x;
  if (idx < WS_WTG) {
    // node weights, per-thread register layout
    int e = idx & 3, r = idx >> 2;
    int t = r & 1023, q = r >> 10;          // q in [0,96)
    int half = t >> 9, m = t & 511;
    int c = q >> 5, kq = q & 31;
    int o = m + (c << 9);
    int k = half * 128 + (kq << 2) + e;
    ws[idx] = (o < 768) ? Wih_node[o * 270 + 14 + k]
                        : Whh_node[(o - 768) * 256 + k];
  } else if (idx < WS_ABN) {
    // graph weights k-major
    int r = idx - WS_WTG;
    int k = r / 1536, o = r % 1536;
    ws[idx] = (o < 768) ? Wih_graph[o * 256 + k]
                        : Whh_graph[(o - 768) * 256 + k];
  } else if (idx < WS_WS1T) {
    int r = idx - WS_ABN;                   // [0, 10752)
    int tab = r / 5376, r2 = r % 5376;
    int c = r2 / 768, o = r2 % 768;
    ws[idx] = (tab == 0) ? (Wih_node[o * 270 + c] + bih_node[o])
                         : Wih_node[o * 270 + 7 + c];
  } else if (idx < WS_PROBS) {
    int r = idx - WS_WS1T;                  // [0, 16384)
    int k = r >> 6, u = r & 63;
    ws[idx] = Ws1[u * 256 + k];             // Ws1t[k][u]
  }
}

// One block (1024 thr) per graph. Node GRU weights live in registers
// (384 fp32/thread across the unified VGPR/AGPR file); h broadcast from LDS.
__global__ __launch_bounds__(1024, 1) void rnn_kernel(
    const float* __restrict__ z,
    const float* __restrict__ nf,
    const float* __restrict__ bhh_node,
    const float* __restrict__ bih_graph,
    const float* __restrict__ bhh_graph,
    const float* __restrict__ bs1,
    const float* __restrict__ Ws2,
    const float* __restrict__ bs2,
    float* __restrict__ ws) {
  __shared__ __align__(16) float ws1t_l[16384];   // 64 KB
  __shared__ float an_l[5376];                    // A table [7][768]
  __shared__ float bn_l[5376];                    // B table [7][768]
  __shared__ float bhhn_l[768];
  __shared__ float bihg_l[768];
  __shared__ float bhhg_l[768];
  __shared__ float bs1_l[64];
  __shared__ float ws2_l[64];
  __shared__ __align__(16) float nh[256];
  __shared__ __align__(16) float gh2[256];
  __shared__ float part[2][1536];
  __shared__ float part2[8][64];
  __shared__ int cls[NN];
  __shared__ float bs2_l;

  const int b = blockIdx.x, t = threadIdx.x;
  float* probs = ws + WS_PROBS + (size_t)b * TT;

  // ---- stage constants into LDS ----
  for (int x = t; x < 5376; x += 1024) {
    an_l[x] = ws[WS_ABN + x];
    bn_l[x] = ws[WS_ABN + 5376 + x];
  }
  for (int x = t; x < 16384; x += 1024) ws1t_l[x] = ws[WS_WS1T + x];
  if (t < 768) {
    bhhn_l[t] = bhh_node[t];
    bihg_l[t] = bih_graph[t];
    bhhg_l[t] = bhh_graph[t];
  }
  if (t < 64) { bs1_l[t] = bs1[t]; ws2_l[t] = Ws2[t]; }
  if (t == 0) bs2_l = bs2[0];
  if (t < NN) {
    const float* row = nf + (b * NN + t) * FF;
    int c = 0;
#pragma unroll
    for (int q = 1; q < FF; ++q)
      if (row[q] > 0.5f) c = q;
    cls[t] = c;
  }
  if (t < 256) { float v = z[b * 256 + t]; nh[t] = v; gh2[t] = v; }

  // ---- load node weights into registers (coalesced float4) ----
  float w[384];  // w[c*128 + kl]: col c of {m, m+512, m+1024}, k-local kl
  {
    const float4* wq = (const float4*)(ws + WS_WREG);
#pragma unroll
    for (int q = 0; q < 96; ++q) {
      float4 v = wq[(q << 10) + t];
      const int c = q >> 5, kl = (q & 31) << 2;
      w[c * 128 + kl + 0] = v.x;
      w[c * 128 + kl + 1] = v.y;
      w[c * 128 + kl + 2] = v.z;
      w[c * 128 + kl + 3] = v.w;
    }
  }
  __syncthreads();

  const int half = t >> 9;       // wave-uniform k-half
  const int m = t & 511;
  const int u = t & 255;
  const int q8 = t >> 6, uu = t & 63;   // MLP-part roles (t<512)
  int base = 0;

  for (int i = 0; i < NN - 1; ++i) {
    const float* Ar = an_l + cls[i] * 768;

    for (int j = i + 1; j < NN; ++j) {
      const float* Br = bn_l + cls[j] * 768;
      // ---- Phase A: register matvec (all threads) + pending MLP-part ----
      float s0 = 0.f, s1 = 0.f, s2 = 0.f;
      const float4* hp = (const float4*)nh + (half << 5);
#pragma unroll
      for (int kq = 0; kq < 32; ++kq) {
        float4 h4 = hp[kq];
        const int kl = kq << 2;
        s0 = fmaf(h4.x, w[kl + 0], s0);
        s0 = fmaf(h4.y, w[kl + 1], s0);
        s0 = fmaf(h4.z, w[kl + 2], s0);
        s0 = fmaf(h4.w, w[kl + 3], s0);
        s1 = fmaf(h4.x, w[128 + kl + 0], s1);
        s1 = fmaf(h4.y, w[128 + kl + 1], s1);
        s1 = fmaf(h4.z, w[128 + kl + 2], s1);
        s1 = fmaf(h4.w, w[128 + kl + 3], s1);
        s2 = fmaf(h4.x, w[256 + kl + 0], s2);
        s2 = fmaf(h4.y, w[256 + kl + 1], s2);
        s2 = fmaf(h4.z, w[256 + kl + 2], s2);
        s2 = fmaf(h4.w, w[256 + kl + 3], s2);
      }
      part[half][m] = s0;
      part[half][m + 512] = s1;
      part[half][m + 1024] = s2;
      if (j > i + 1 && t < 512) {   // MLP hidden-part for prob (i, j-1)
        float p = 0.f;
        const int k0 = q8 << 5;
#pragma unroll
        for (int kk = 0; kk < 32; ++kk)
          p = fmaf(nh[k0 + kk], ws1t_l[((k0 + kk) << 6) + uu], p);
        part2[q8][uu] = p;
      }
      __syncthreads();
      // ---- Phase B: GRU nonlinearity + pending MLP-reduce ----
      if (t < 256) {
        float ir = part[0][u] + part[1][u] + Ar[u] + Br[u];
        float iz = part[0][256 + u] + part[1][256 + u] + Ar[256 + u] + Br[256 + u];
        float in_ = part[0][512 + u] + part[1][512 + u] + Ar[512 + u] + Br[512 + u];
        float hr = part[0][768 + u] + part[1][768 + u] + bhhn_l[u];
        float hz = part[0][1024 + u] + part[1][1024 + u] + bhhn_l[256 + u];
        float hn = part[0][1280 + u] + part[1][1280 + u] + bhhn_l[512 + u];
        float ho = nh[u];
        float r = 1.f / (1.f + expf(-(ir + hr)));
        float zg = 1.f / (1.f + expf(-(iz + hz)));
        float n2 = tanhf(in_ + r * hn);
        nh[u] = (1.f - zg) * n2 + zg * ho;
      } else if (j > i + 1 && t >= 960) {
        int v = t - 960;
        float hv = part2[0][v] + part2[1][v] + part2[2][v] + part2[3][v] +
                   part2[4][v] + part2[5][v] + part2[6][v] + part2[7][v] + bs1_l[v];
        hv = fmaxf(hv, 0.f);
        float c2 = hv * ws2_l[v];
#pragma unroll
        for (int off = 32; off > 0; off >>= 1)
          c2 += __shfl_down(c2, off);
        if (v == 0)
          probs[base + j - i - 2] = 1.f / (1.f + expf(-(c2 + bs2_l)));
      }
      __syncthreads();
    }

    // ---- Graph GRU step (weights streamed from L2) ----
    {
      // Phase A': matvec (t<768, 2 outputs each) + MLP-part for (i, NN-1)
      if (t < 768) {
        const int o0 = t << 1;
        const float* hv_src = (o0 < 768) ? nh : gh2;   // wave-uniform
        const float* wp = ws + WS_WTG + o0;
        float s0 = 0.f, s1 = 0.f;
#pragma unroll 8
        for (int k = 0; k < 256; ++k) {
          float hk = hv_src[k];
          float2 wv = *(const float2*)(wp + (size_t)k * 1536);
          s0 = fmaf(hk, wv.x, s0);
          s1 = fmaf(hk, wv.y, s1);
        }
        part[0][o0] = s0;
        part[0][o0 + 1] = s1;
      }
      if (t < 512) {
        float p = 0.f;
        const int k0 = q8 << 5;
#pragma unroll
        for (int kk = 0; kk < 32; ++kk)
          p = fmaf(nh[k0 + kk], ws1t_l[((k0 + kk) << 6) + uu], p);
        part2[q8][uu] = p;
      }
      __syncthreads();
      // Phase B': graph nonlinearity + final MLP-reduce of this row
      if (t < 256) {
        float ir = part[0][u] + bihg_l[u];
        float iz = part[0][256 + u] + bihg_l[256 + u];
        float in_ = part[0][512 + u] + bihg_l[512 + u];
        float hr = part[0][768 + u] + bhhg_l[u];
        float hz = part[0][1024 + u] + bhhg_l[256 + u];
        float hn = part[0][1280 + u] + bhhg_l[512 + u];
        float ho = gh2[u];
        float r = 1.f / (1.f + expf(-(ir + hr)));
        float zg = 1.f / (1.f + expf(-(iz + hz)));
        float n2 = tanhf(in_ + r * hn);
        float nv = (1.f - zg) * n2 + zg * ho;
        gh2[u] = nv;
        nh[u] = nv;   // node_h for next outer step starts from graph_h
      } else if (t >= 960) {
        int v = t - 960;
        float hv = part2[0][v] + part2[1][v] + part2[2][v] + part2[3][v] +
                   part2[4][v] + part2[5][v] + part2[6][v] + part2[7][v] + bs1_l[v];
        hv = fmaxf(hv, 0.f);
        float c2 = hv * ws2_l[v];
#pragma unroll
        for (int off = 32; off > 0; off >>= 1)
          c2 += __shfl_down(c2, off);
        if (v == 0)
          probs[base + NN - 2 - i] = 1.f / (1.f + expf(-(c2 + bs2_l)));
      }
      __syncthreads();
    }
    base += NN - 1 - i;
  }
}

// ContinuousBernoulli icdf + anti-diagonal scatter into adj
__global__ void edges_kernel(const float* __restrict__ u,
                             const float* __restrict__ ws,
                             float* __restrict__ adj) {
  int idx = blockIdx.x * blockDim.x + threadIdx.x;
  if (idx >= BB * TT) return;
  int b = idx / TT, t = idx % TT;
  float prob = ws[WS_PROBS + (size_t)b * TT + t];
  float uu = u[idx];
  const float EPSF = 1.1920929e-07f;
  float p = fminf(fmaxf(prob, EPSF), 1.0f - EPSF);
  bool outside = (p < 0.499f) || (p > 0.501f);
  float cut = outside ? p : 0.499f;
  float stable = (log1pf(fmaf(uu, 2.f * cut - 1.f, -cut)) - log1pf(-cut)) /
                 (logf(cut) - log1pf(-cut));
  float e = outside ? stable : uu;
  // t-th row-major triu edge lands at the t-th anti-diagonal slot:
  // diagonals d=1..31, entry k=0..d-1 -> (k, k + N - d)
  int d = (int)((1.0f + sqrtf(1.0f + 8.0f * (float)t)) * 0.5f);
  while (d * (d + 1) / 2 <= t) ++d;
  while (d * (d - 1) / 2 > t) --d;
  int k = t - d * (d - 1) / 2;
  int r = k, c = k + (NN - d);
  adj[((size_t)b * NN + r) * NN + c] = e;
  adj[((size_t)b * NN + c) * NN + r] = e;
}

__global__ void xb_kernel(const float* __restrict__ nf,
                          float* __restrict__ out_x,
                          float* __restrict__ out_batch) {
  int idx = blockIdx.x * blockDim.x + threadIdx.x;
  if (idx < BB * NN * FF) out_x[idx] = nf[idx];
  // batch output is read back as float32 (whole d_out is one dtype):
  // write float values 0..255, repeat(arange(B), N)
  if (idx < BB * NN) out_batch[idx] = (float)(idx >> 5);
}

extern "C" void kernel_launch(void* const* d_in, const int* in_sizes, int n_in,
                              void* d_out, int out_size, void* d_ws, size_t ws_size,
                              hipStream_t stream) {
  const float* z         = (const float*)d_in[0];
  const float* nf        = (const float*)d_in[1];
  const float* u         = (const float*)d_in[2];
  const float* Wih_node  = (const float*)d_in[3];
  const float* Whh_node  = (const float*)d_in[4];
  const float* bih_node  = (const float*)d_in[5];
  const float* bhh_node  = (const float*)d_in[6];
  const float* Wih_graph = (const float*)d_in[7];
  const float* Whh_graph = (const float*)d_in[8];
  const float* bih_graph = (const float*)d_in[9];
  const float* bhh_graph = (const float*)d_in[10];
  const float* Ws1       = (const float*)d_in[11];
  const float* bs1       = (const float*)d_in[12];
  const float* Ws2       = (const float*)d_in[13];
  const float* bs2       = (const float*)d_in[14];

  float* ws = (float*)d_ws;
  float* out_x   = (float*)d_out;                       // [B*N, F]
  float* out_adj = out_x + BB * NN * FF;                // [B, N, N]
  float* out_batch = out_x + BB * NN * FF + (size_t)BB * NN * NN;

  hipMemsetAsync(out_adj, 0, (size_t)BB * NN * NN * sizeof(float), stream);
  prep_kernel<<<PREP_TOTAL / 256, 256, 0, stream>>>(
      Wih_node, Whh_node, bih_node, Wih_graph, Whh_graph, Ws1, ws);
  rnn_kernel<<<BB, 1024, 0, stream>>>(
      z, nf, bhh_node, bih_graph, bhh_graph, bs1, Ws2, bs2, ws);
  xb_kernel<<<(BB * NN * FF + 255) / 256, 256, 0, stream>>>(nf, out_x, out_batch);
  edges_kernel<<<(BB * TT + 255) / 256, 256, 0, stream>>>(u, ws, out_adj);
}

// Round 4
// 3489.022 us; speedup vs baseline: 10.2221x; 10.2221x over previous
//
#include <hip/hip_runtime.h>
#include <hip/hip_fp16.h>
#include <math.h>

// Problem constants
#define BB 256
#define NN 32
#define HH 256
#define FF 7
#define TT 496

typedef _Float16 f16x2 __attribute__((ext_vector_type(2)));
typedef _Float16 f16x4 __attribute__((ext_vector_type(4)));
typedef _Float16 f16x8 __attribute__((ext_vector_type(8)));

// ---- workspace layout ----
// Node GRU uses COMBINED weights W_eff[k][o], o in [0,1024):
//   o<256: r-gate (Wih_h + Whh), o in [256,512): z-gate (Wih_h + Whh),
//   o in [512,768): i_n (Wih_h), o in [768,1024): h_n (Whh row o-256).
// K-zones: k in [0,64) fp32 in registers, [64,100) fp16 in LDS, [100,256) fp16 streamed.
// float offsets:
#define WS_WREG   0         // 65536 f32: reg blob, float4 elem = wb[cq*1024 + t], cq=q*4+c
#define WS_WLDS   65536     // 36864 halves: [kk][oc][4] (kk<36, k=64+kk)
#define WS_WSTR   83968     // 159744 halves: [kk][oc][4] (kk<156, k=100+kk)
#define WS_WTG    163840    // 393216 halves: graph weights [k][1536] k-major
#define WS_AB     360448    // 10752 halves: A2[7][768] then B2[7][768]
#define WS_HB     365824    // 256 f32: bhh_node[512+u]
#define WS_GB     366080    // 1536 halves: bih_graph[768], bhh_graph[768]
#define WS_WS1    366848    // 16384 halves: [(kq*64+u2)*16 + kk] = Ws1[u2][kq*16+kk]
#define WS_PROBS  375040    // 126976 f32
// half offsets (2x float offsets)
#define WS_WLDS_H 131072
#define WS_WSTR_H 167936
#define WS_WTG_H  327680
#define WS_AB_H   720896
#define WS_GB_H   732160
#define WS_WS1_H  733696

// prep virtual index space (elements)
#define SEG1 65536
#define SEG2 102400   // +36864
#define SEG3 262144   // +159744
#define SEG4 655360   // +393216
#define SEG5 666112   // +10752
#define SEG6 666368   // +256
#define SEG7 667904   // +1536
#define PREP_N 684288 // +16384

__device__ __forceinline__ float weff(const float* Wih, const float* Whh, int k, int o) {
  if (o < 512) return Wih[o * 270 + 14 + k] + Whh[o * 256 + k];
  if (o < 768) return Wih[o * 270 + 14 + k];
  return Whh[(o - 256) * 256 + k];
}

__global__ void prep_kernel(const float* __restrict__ Wih_node,
                            const float* __restrict__ Whh_node,
                            const float* __restrict__ bih_node,
                            const float* __restrict__ bhh_node,
                            const float* __restrict__ Wih_graph,
                            const float* __restrict__ Whh_graph,
                            const float* __restrict__ bih_graph,
                            const float* __restrict__ bhh_graph,
                            const float* __restrict__ Ws1,
                            float* __restrict__ ws) {
  int idx = blockIdx.x * blockDim.x + threadIdx.x;
  if (idx >= PREP_N) return;
  __half* hw = (__half*)ws;
  if (idx < SEG1) {
    // register blob (fp32)
    int e = idx & 3, f4 = idx >> 2;
    int t = f4 & 1023, cq = f4 >> 10;       // cq in [0,16)
    int q = cq >> 2, c = cq & 3;
    int kp = t >> 8, oc = t & 255;
    int k = kp * 16 + c * 4 + e;
    int o = oc + (q << 8);
    ws[WS_WREG + idx] = weff(Wih_node, Whh_node, k, o);
  } else if (idx < SEG2) {
    int i = idx - SEG1;                     // [kk][oc][4] halves
    int q = i & 3, oc = (i >> 2) & 255, kk = i >> 10;   // kk<36
    hw[WS_WLDS_H + i] = __float2half(weff(Wih_node, Whh_node, 64 + kk, oc + (q << 8)));
  } else if (idx < SEG3) {
    int i = idx - SEG2;
    int q = i & 3, oc = (i >> 2) & 255, kk = i >> 10;   // kk<156
    hw[WS_WSTR_H + i] = __float2half(weff(Wih_node, Whh_node, 100 + kk, oc + (q << 8)));
  } else if (idx < SEG4) {
    int i = idx - SEG3;                     // graph [k][1536]
    int k = i / 1536, o = i % 1536;
    float v = (o < 768) ? Wih_graph[o * 256 + k] : Whh_graph[(o - 768) * 256 + k];
    hw[WS_WTG_H + i] = __float2half(v);
  } else if (idx < SEG5) {
    int i = idx - SEG4;
    float v;
    if (i < 5376) {                         // A2[ci][o]
      int ci = i / 768, o = i % 768;
      v = Wih_node[o * 270 + ci] + bih_node[o] + ((o < 512) ? bhh_node[o] : 0.f);
    } else {                                // B2[cj][o]
      int i2 = i - 5376;
      int cj = i2 / 768, o = i2 % 768;
      v = Wih_node[o * 270 + 7 + cj];
    }
    hw[WS_AB_H + i] = __float2half(v);
  } else if (idx < SEG6) {
    int u = idx - SEG5;
    ws[WS_HB + u] = bhh_node[512 + u];
  } else if (idx < SEG7) {
    int i = idx - SEG6;
    float v = (i < 768) ? bih_graph[i] : bhh_graph[i - 768];
    hw[WS_GB_H + i] = __float2half(v);
  } else {
    int i = idx - SEG7;                     // ws1 packed [(kq*64+u2)*16+kk]
    int kk = i & 15, r = i >> 4;
    int u2 = r & 63, kq = r >> 6;
    hw[WS_WS1_H + i] = __float2half(Ws1[u2 * 256 + kq * 16 + kk]);
  }
}

#define RCHUNK(c, A_, B_, C_, D_) { \
  float4 h4 = nh4[(kp << 2) + c]; \
  s0 = fmaf(h4.x, A_.x, s0); s0 = fmaf(h4.y, A_.y, s0); s0 = fmaf(h4.z, A_.z, s0); s0 = fmaf(h4.w, A_.w, s0); \
  s1 = fmaf(h4.x, B_.x, s1); s1 = fmaf(h4.y, B_.y, s1); s1 = fmaf(h4.z, B_.z, s1); s1 = fmaf(h4.w, B_.w, s1); \
  s2 = fmaf(h4.x, C_.x, s2); s2 = fmaf(h4.y, C_.y, s2); s2 = fmaf(h4.z, C_.z, s2); s2 = fmaf(h4.w, C_.w, s2); \
  s3 = fmaf(h4.x, D_.x, s3); s3 = fmaf(h4.y, D_.y, s3); s3 = fmaf(h4.z, D_.z, s3); s3 = fmaf(h4.w, D_.w, s3); }

#define STERM(hc, wv) { \
  s0 = fmaf(hc, (float)wv[0], s0); s1 = fmaf(hc, (float)wv[1], s1); \
  s2 = fmaf(hc, (float)wv[2], s2); s3 = fmaf(hc, (float)wv[3], s3); }

#define MLPPART() { \
  const int u2_ = t & 63, kq_ = t >> 6; \
  const f16x8* wp1_ = (const f16x8*)s_ws1 + (kq_ * 64 + u2_) * 2; \
  f16x8 wa_ = wp1_[0], wb_ = wp1_[1]; \
  const float4* nhm_ = (const float4*)nh + (kq_ << 2); \
  float4 ha_ = nhm_[0], hb_ = nhm_[1], hc_ = nhm_[2], hd_ = nhm_[3]; \
  float p_ = ha_.x*(float)wa_[0] + ha_.y*(float)wa_[1] + ha_.z*(float)wa_[2] + ha_.w*(float)wa_[3] \
           + hb_.x*(float)wa_[4] + hb_.y*(float)wa_[5] + hb_.z*(float)wa_[6] + hb_.w*(float)wa_[7] \
           + hc_.x*(float)wb_[0] + hc_.y*(float)wb_[1] + hc_.z*(float)wb_[2] + hc_.w*(float)wb_[3] \
           + hd_.x*(float)wb_[4] + hd_.y*(float)wb_[5] + hd_.z*(float)wb_[6] + hd_.w*(float)wb_[7]; \
  part2[kq_][u2_] = p_; }

#define MLPRED(dst) { \
  int v_ = t - 960; \
  float hv_ = part2[0][v_]+part2[1][v_]+part2[2][v_]+part2[3][v_] \
            + part2[4][v_]+part2[5][v_]+part2[6][v_]+part2[7][v_] \
            + part2[8][v_]+part2[9][v_]+part2[10][v_]+part2[11][v_] \
            + part2[12][v_]+part2[13][v_]+part2[14][v_]+part2[15][v_] + s_bs1[v_]; \
  hv_ = fmaxf(hv_, 0.f); \
  float c2_ = hv_ * s_ws2[v_]; \
  for (int off_ = 32; off_ > 0; off_ >>= 1) c2_ += __shfl_down(c2_, off_); \
  if (v_ == 0) dst = 1.f / (1.f + expf(-(c2_ + s_bs2))); }

__global__ __launch_bounds__(1024) void rnn_kernel(
    const float* __restrict__ z,
    const float* __restrict__ nf,
    const float* __restrict__ bs1,
    const float* __restrict__ Ws2,
    const float* __restrict__ bs2,
    float* __restrict__ ws) {
  __shared__ __align__(16) __half s_wl[36864];   // 72 KB: stream-free LDS weight zone
  __shared__ __align__(16) __half s_a2[5376];
  __shared__ __align__(16) __half s_b2[5376];
  __shared__ __align__(16) __half s_gbi[768];
  __shared__ __align__(16) __half s_gbh[768];
  __shared__ __align__(16) __half s_ws1[16384];  // 32 KB
  __shared__ __align__(16) float s_hb[256];
  __shared__ float s_bs1[64], s_ws2[64];
  __shared__ __align__(16) float nh[256];
  __shared__ __align__(16) float gh2[256];
  __shared__ __align__(16) float part[4][1024];  // 16 KB
  __shared__ __align__(16) float part2[16][64];  // 4 KB
  __shared__ int cls[NN];
  __shared__ float s_bs2;

  const int b = blockIdx.x, t = threadIdx.x;
  const __half* hws = (const __half*)ws;
  float* probs = ws + WS_PROBS + (size_t)b * TT;

  // ---- stage LDS ----
  for (int x = t; x < 36864; x += 1024) s_wl[x] = hws[WS_WLDS_H + x];
  for (int x = t; x < 5376; x += 1024) {
    s_a2[x] = hws[WS_AB_H + x];
    s_b2[x] = hws[WS_AB_H + 5376 + x];
  }
  for (int x = t; x < 16384; x += 1024) s_ws1[x] = hws[WS_WS1_H + x];
  if (t < 768) {
    s_gbi[t] = hws[WS_GB_H + t];
    s_gbh[t] = hws[WS_GB_H + 768 + t];
  }
  if (t < 256) {
    s_hb[t] = ws[WS_HB + t];
    float v = z[b * 256 + t];
    nh[t] = v; gh2[t] = v;
  }
  if (t < 64) { s_bs1[t] = bs1[t]; s_ws2[t] = Ws2[t]; }
  if (t == 0) s_bs2 = bs2[0];
  if (t < NN) {
    const float* row = nf + (b * NN + t) * FF;
    int c = 0;
#pragma unroll
    for (int q = 1; q < FF; ++q)
      if (row[q] > 0.5f) c = q;
    cls[t] = c;
  }

  // ---- load fp32 register weights (16 named float4 = 64 VGPR, SSA: cannot spill silently) ----
  const float4* wb = (const float4*)(ws + WS_WREG);
  float4 W00 = wb[0 * 1024 + t], W01 = wb[1 * 1024 + t], W02 = wb[2 * 1024 + t], W03 = wb[3 * 1024 + t];
  float4 W10 = wb[4 * 1024 + t], W11 = wb[5 * 1024 + t], W12 = wb[6 * 1024 + t], W13 = wb[7 * 1024 + t];
  float4 W20 = wb[8 * 1024 + t], W21 = wb[9 * 1024 + t], W22 = wb[10 * 1024 + t], W23 = wb[11 * 1024 + t];
  float4 W30 = wb[12 * 1024 + t], W31 = wb[13 * 1024 + t], W32 = wb[14 * 1024 + t], W33 = wb[15 * 1024 + t];
  __syncthreads();

  const int kp = t >> 8;      // k-partition (wave-uniform)
  const int oc = t & 255;     // output column; outputs oc+256q, q=0..3
  int base = 0;

  for (int i = 0; i < NN - 1; ++i) {
    const __half* ArH = s_a2 + cls[i] * 768;

    for (int j = i + 1; j < NN; ++j) {
      const __half* BrH = s_b2 + cls[j] * 768;
      const bool pend = (j > i + 1);
      // ================= Phase A: matvec over all k-zones =================
      float s0 = 0.f, s1 = 0.f, s2 = 0.f, s3 = 0.f;
      const float4* nh4 = (const float4*)nh;
      RCHUNK(0, W00, W10, W20, W30)
      RCHUNK(1, W01, W11, W21, W31)
      RCHUNK(2, W02, W12, W22, W32)
      RCHUNK(3, W03, W13, W23, W33)
      {
        // LDS fp16 zone: k in [64+kp*9, +9)
        const f16x4* wl = (const f16x4*)s_wl + (kp * 9) * 256 + oc;
        const float* hl = nh + 64 + kp * 9;
#pragma unroll
        for (int s = 0; s < 9; ++s) {
          f16x4 wv = wl[s * 256];
          float hk = hl[s];
          STERM(hk, wv)
        }
      }
      {
        // streamed fp16 zone: k in [100+kp*40, +40) (kp=3: 36)
        const int nc = (kp < 3) ? 10 : 9;
        const f16x4* gsp = (const f16x4*)(hws + WS_WSTR_H) + (kp * 40) * 256 + oc;
        const float4* hs4 = (const float4*)(nh + 100 + kp * 40);
        for (int c = 0; c < nc; ++c) {
          float4 h4 = hs4[c];
          f16x4 wa = gsp[(c * 4 + 0) * 256];
          f16x4 wbv = gsp[(c * 4 + 1) * 256];
          f16x4 wcv = gsp[(c * 4 + 2) * 256];
          f16x4 wd = gsp[(c * 4 + 3) * 256];
          STERM(h4.x, wa)
          STERM(h4.y, wbv)
          STERM(h4.z, wcv)
          STERM(h4.w, wd)
        }
      }
      part[kp][oc] = s0;
      part[kp][oc + 256] = s1;
      part[kp][oc + 512] = s2;
      part[kp][oc + 768] = s3;
      if (pend) MLPPART()         // MLP hidden-part for prob (i, j-1)
      __syncthreads();
      // ================= Phase B: nonlinearity + MLP reduce =================
      if (t < 256) {
        const int u = t;
        float pr  = part[0][u]       + part[1][u]       + part[2][u]       + part[3][u];
        float pz  = part[0][256 + u] + part[1][256 + u] + part[2][256 + u] + part[3][256 + u];
        float pin = part[0][512 + u] + part[1][512 + u] + part[2][512 + u] + part[3][512 + u];
        float phn = part[0][768 + u] + part[1][768 + u] + part[2][768 + u] + part[3][768 + u];
        float ar = (float)ArH[u]       + (float)BrH[u];
        float az = (float)ArH[256 + u] + (float)BrH[256 + u];
        float an = (float)ArH[512 + u] + (float)BrH[512 + u];
        float r  = 1.f / (1.f + expf(-(pr + ar)));
        float zg = 1.f / (1.f + expf(-(pz + az)));
        float n2 = tanhf(pin + an + r * (phn + s_hb[u]));
        nh[u] = (1.f - zg) * n2 + zg * nh[u];
      } else if (pend && t >= 960) {
        MLPRED(probs[base + j - i - 2])
      }
      __syncthreads();
    }

    // ================= Graph GRU step (fp16 weights streamed from L2) =================
    {
      if (t < 768) {
        const int o0 = t << 1;
        const float* hv = (o0 < 768) ? nh : gh2;     // wave-uniform split at t=384
        const float4* hv4 = (const float4*)hv;
        const f16x2* wg = (const f16x2*)(hws + WS_WTG_H) + t;
        float g0 = 0.f, g1 = 0.f;
#pragma unroll 2
        for (int kb = 0; kb < 64; ++kb) {
          float4 h4 = hv4[kb];
          f16x2 w0 = wg[(kb * 4 + 0) * 768];
          f16x2 w1 = wg[(kb * 4 + 1) * 768];
          f16x2 w2 = wg[(kb * 4 + 2) * 768];
          f16x2 w3 = wg[(kb * 4 + 3) * 768];
          g0 = fmaf(h4.x, (float)w0[0], g0); g1 = fmaf(h4.x, (float)w0[1], g1);
          g0 = fmaf(h4.y, (float)w1[0], g0); g1 = fmaf(h4.y, (float)w1[1], g1);
          g0 = fmaf(h4.z, (float)w2[0], g0); g1 = fmaf(h4.z, (float)w2[1], g1);
          g0 = fmaf(h4.w, (float)w3[0], g0); g1 = fmaf(h4.w, (float)w3[1], g1);
        }
        ((float*)part)[o0] = g0;
        ((float*)part)[o0 + 1] = g1;
      }
      MLPPART()                   // MLP hidden-part for prob (i, NN-1)
      __syncthreads();
      if (t < 256) {
        const int u = t;
        const float* pf = (const float*)part;
        float gir = pf[u]        + (float)s_gbi[u];
        float giz = pf[256 + u]  + (float)s_gbi[256 + u];
        float gin = pf[512 + u]  + (float)s_gbi[512 + u];
        float ghr = pf[768 + u]  + (float)s_gbh[u];
        float ghz = pf[1024 + u] + (float)s_gbh[256 + u];
        float ghn = pf[1280 + u] + (float)s_gbh[512 + u];
        float r  = 1.f / (1.f + expf(-(gir + ghr)));
        float zg = 1.f / (1.f + expf(-(giz + ghz)));
        float n2 = tanhf(gin + r * ghn);
        float nv = (1.f - zg) * n2 + zg * gh2[u];
        gh2[u] = nv;
        nh[u] = nv;               // node_h for next row starts from graph_h
      } else if (t >= 960) {
        MLPRED(probs[base + NN - 2 - i])
      }
      __syncthreads();
    }
    base += NN - 1 - i;
  }
}

// ContinuousBernoulli icdf + anti-diagonal scatter into adj
__global__ void edges_kernel(const float* __restrict__ u,
                             const float* __restrict__ ws,
                             float* __restrict__ adj) {
  int idx = blockIdx.x * blockDim.x + threadIdx.x;
  if (idx >= BB * TT) return;
  int b = idx / TT, t = idx % TT;
  float prob = ws[WS_PROBS + (size_t)b * TT + t];
  float uu = u[idx];
  const float EPSF = 1.1920929e-07f;
  float p = fminf(fmaxf(prob, EPSF), 1.0f - EPSF);
  bool outside = (p < 0.499f) || (p > 0.501f);
  float cut = outside ? p : 0.499f;
  float stable = (log1pf(fmaf(uu, 2.f * cut - 1.f, -cut)) - log1pf(-cut)) /
                 (logf(cut) - log1pf(-cut));
  float e = outside ? stable : uu;
  int d = (int)((1.0f + sqrtf(1.0f + 8.0f * (float)t)) * 0.5f);
  while (d * (d + 1) / 2 <= t) ++d;
  while (d * (d - 1) / 2 > t) --d;
  int k = t - d * (d - 1) / 2;
  int r = k, c = k + (NN - d);
  adj[((size_t)b * NN + r) * NN + c] = e;
  adj[((size_t)b * NN + c) * NN + r] = e;
}

__global__ void xb_kernel(const float* __restrict__ nf,
                          float* __restrict__ out_x,
                          float* __restrict__ out_batch) {
  int idx = blockIdx.x * blockDim.x + threadIdx.x;
  if (idx < BB * NN * FF) out_x[idx] = nf[idx];
  if (idx < BB * NN) out_batch[idx] = (float)(idx >> 5);
}

extern "C" void kernel_launch(void* const* d_in, const int* in_sizes, int n_in,
                              void* d_out, int out_size, void* d_ws, size_t ws_size,
                              hipStream_t stream) {
  const float* z         = (const float*)d_in[0];
  const float* nf        = (const float*)d_in[1];
  const float* u         = (const float*)d_in[2];
  const float* Wih_node  = (const float*)d_in[3];
  const float* Whh_node  = (const float*)d_in[4];
  const float* bih_node  = (const float*)d_in[5];
  const float* bhh_node  = (const float*)d_in[6];
  const float* Wih_graph = (const float*)d_in[7];
  const float* Whh_graph = (const float*)d_in[8];
  const float* bih_graph = (const float*)d_in[9];
  const float* bhh_graph = (const float*)d_in[10];
  const float* Ws1       = (const float*)d_in[11];
  const float* bs1       = (const float*)d_in[12];
  const float* Ws2       = (const float*)d_in[13];
  const float* bs2       = (const float*)d_in[14];

  float* ws = (float*)d_ws;
  float* out_x   = (float*)d_out;                        // [B*N, F]
  float* out_adj = out_x + BB * NN * FF;                 // [B, N, N]
  float* out_batch = out_x + BB * NN * FF + (size_t)BB * NN * NN;

  hipMemsetAsync(out_adj, 0, (size_t)BB * NN * NN * sizeof(float), stream);
  prep_kernel<<<(PREP_N + 255) / 256, 256, 0, stream>>>(
      Wih_node, Whh_node, bih_node, bhh_node,
      Wih_graph, Whh_graph, bih_graph, bhh_graph, Ws1, ws);
  rnn_kernel<<<BB, 1024, 0, stream>>>(z, nf, bs1, Ws2, bs2, ws);
  xb_kernel<<<(BB * NN * FF + 255) / 256, 256, 0, stream>>>(nf, out_x, out_batch);
  edges_kernel<<<(BB * TT + 255) / 256, 256, 0, stream>>>(u, ws, out_adj);
}

// Round 5
// 2707.400 us; speedup vs baseline: 13.1731x; 1.2887x over previous
//
#include <hip/hip_runtime.h>
#include <hip/hip_fp16.h>
#include <math.h>

// Problem constants
#define BB 256
#define NN 32
#define HH 256
#define FF 7
#define TT 496

typedef _Float16 f16x2 __attribute__((ext_vector_type(2)));
typedef _Float16 f16x4 __attribute__((ext_vector_type(4)));
typedef _Float16 f16x8 __attribute__((ext_vector_type(8)));

#if defined(__has_builtin)
#  if __has_builtin(__builtin_amdgcn_fdot2)
#    define HAS_FDOT2 1
#  endif
#endif

__device__ __forceinline__ float dot2f(f16x2 a, f16x2 b, float c) {
#ifdef HAS_FDOT2
  return __builtin_amdgcn_fdot2(a, b, c, false);
#else
  return fmaf((float)a[1], (float)b[1], fmaf((float)a[0], (float)b[0], c));
#endif
}

#define SH2(V, L) __builtin_shufflevector(V, V, 2 * (L), 2 * (L) + 1)
#define SH01(V) __builtin_shufflevector(V, V, 0, 1)
#define SH23(V) __builtin_shufflevector(V, V, 2, 3)

// ---- workspace layout ----
// Node GRU combined weights W_eff[k][o], o in [0,1024):
//   o<256: r (Wih_h+Whh), [256,512): z (Wih_h+Whh), [512,768): i_n (Wih_h),
//   [768,1024): h_n (Whh rows 512..768)
// Per-thread (kp = t>>8 covers k in [kp*64, +64), oc = t&255 covers outputs oc+256q):
//   k-local [0,24): registers (12 f16x8), [24,32): LDS, [32,64): streamed from L2.
// Half-index offsets:
#define H_WREG 0         // [kp][12][256] f16x8 = 98304 halves
#define H_WLDS 98304     // [kp][4][256]  f16x8 = 32768
#define H_WSTR 131072    // [kp][16][256] f16x8 = 131072
#define H_WTG  262144    // [128 kpair][768 oc2] f16x4 {k0o0,k1o0,k0o1,k1o1} = 393216
#define H_AB   655360    // A2[7][768] then B2[7][768] = 10752
#define H_GB   666112    // bih_graph[768], bhh_graph[768] = 1536
#define H_WS1  667648    // [(kq*64+u2)*16+kk] = Ws1[u2][kq*16+kk] = 16384
// Float-index offsets:
#define F_HB    342016   // 256 f32: bhh_node[512+u]
#define F_PROBS 342272   // 256*496 f32

// prep element-index segments
#define S_WREG_END 98304
#define S_WLDS_END 131072
#define S_WSTR_END 262144
#define S_WTG_END  655360
#define S_AB_END   666112
#define S_GB_END   667648
#define S_WS1_END  684032
#define PREP_N     684288   // +256 HB floats

__device__ __forceinline__ float weff(const float* Wih, const float* Whh, int k, int o) {
  if (o < 512) return Wih[o * 270 + 14 + k] + Whh[o * 256 + k];
  if (o < 768) return Wih[o * 270 + 14 + k];
  return Whh[(o - 256) * 256 + k];
}

__global__ void prep_kernel(const float* __restrict__ Wih_node,
                            const float* __restrict__ Whh_node,
                            const float* __restrict__ bih_node,
                            const float* __restrict__ bhh_node,
                            const float* __restrict__ Wih_graph,
                            const float* __restrict__ Whh_graph,
                            const float* __restrict__ bih_graph,
                            const float* __restrict__ bhh_graph,
                            const float* __restrict__ Ws1,
                            float* __restrict__ ws) {
  int idx = blockIdx.x * blockDim.x + threadIdx.x;
  if (idx >= PREP_N) return;
  __half* hw = (__half*)ws;
  if (idx < S_WREG_END) {
    int e = idx & 7, s = idx >> 3;
    int oc = s & 255, r = s >> 8;
    int pr = r % 12, kp = r / 12;
    int q = e >> 1, kb = e & 1;
    int k = kp * 64 + pr * 2 + kb;
    int o = oc + (q << 8);
    hw[H_WREG + idx] = __float2half(weff(Wih_node, Whh_node, k, o));
  } else if (idx < S_WLDS_END) {
    int i = idx - S_WREG_END;
    int e = i & 7, s = i >> 3;
    int oc = s & 255, r = s >> 8;
    int pr = r % 4, kp = r / 4;
    int q = e >> 1, kb = e & 1;
    int k = kp * 64 + 24 + pr * 2 + kb;
    int o = oc + (q << 8);
    hw[H_WLDS + i] = __float2half(weff(Wih_node, Whh_node, k, o));
  } else if (idx < S_WSTR_END) {
    int i = idx - S_WLDS_END;
    int e = i & 7, s = i >> 3;
    int oc = s & 255, r = s >> 8;
    int pr = r % 16, kp = r / 16;
    int q = e >> 1, kb = e & 1;
    int k = kp * 64 + 32 + pr * 2 + kb;
    int o = oc + (q << 8);
    hw[H_WSTR + i] = __float2half(weff(Wih_node, Whh_node, k, o));
  } else if (idx < S_WTG_END) {
    int i = idx - S_WSTR_END;
    int e = i & 3, s = i >> 2;
    int kb = e & 1, ob = e >> 1;
    int oc2 = s % 768, kpair = s / 768;
    int k = 2 * kpair + kb, o = 2 * oc2 + ob;
    float v = (o < 768) ? Wih_graph[o * 256 + k] : Whh_graph[(o - 768) * 256 + k];
    hw[H_WTG + i] = __float2half(v);
  } else if (idx < S_AB_END) {
    int i = idx - S_WTG_END;
    float v;
    if (i < 5376) {
      int ci = i / 768, o = i % 768;
      v = Wih_node[o * 270 + ci] + bih_node[o] + ((o < 512) ? bhh_node[o] : 0.f);
    } else {
      int i2 = i - 5376;
      int cj = i2 / 768, o = i2 % 768;
      v = Wih_node[o * 270 + 7 + cj];
    }
    hw[H_AB + i] = __float2half(v);
  } else if (idx < S_GB_END) {
    int i = idx - S_AB_END;
    float v = (i < 768) ? bih_graph[i] : bhh_graph[i - 768];
    hw[H_GB + i] = __float2half(v);
  } else if (idx < S_WS1_END) {
    int i = idx - S_GB_END;
    int kk = i & 15, r = i >> 4;
    int u2 = r & 63, kq = r >> 6;
    hw[H_WS1 + i] = __float2half(Ws1[u2 * 256 + kq * 16 + kk]);
  } else {
    int u = idx - S_WS1_END;
    ws[F_HB + u] = bhh_node[512 + u];
  }
}

#define PAIR(Wv, Hv, L) { \
  f16x2 h2_ = SH2(Hv, L); \
  s0 = dot2f(h2_, SH2(Wv, 0), s0); \
  s1 = dot2f(h2_, SH2(Wv, 1), s1); \
  s2 = dot2f(h2_, SH2(Wv, 2), s2); \
  s3 = dot2f(h2_, SH2(Wv, 3), s3); }

#define MLPPART() { \
  const int u2_ = t & 63, kq_ = t >> 6; \
  const f16x8* w1p_ = (const f16x8*)s_ws1 + ((kq_ << 6) + u2_) * 2; \
  f16x8 wa_ = w1p_[0], wb_ = w1p_[1]; \
  const f16x8* nhp_ = (const f16x8*)nh2 + (kq_ << 1); \
  f16x8 ha_ = nhp_[0], hb_ = nhp_[1]; \
  float p_ = 0.f; \
  p_ = dot2f(SH2(ha_, 0), SH2(wa_, 0), p_); \
  p_ = dot2f(SH2(ha_, 1), SH2(wa_, 1), p_); \
  p_ = dot2f(SH2(ha_, 2), SH2(wa_, 2), p_); \
  p_ = dot2f(SH2(ha_, 3), SH2(wa_, 3), p_); \
  p_ = dot2f(SH2(hb_, 0), SH2(wb_, 0), p_); \
  p_ = dot2f(SH2(hb_, 1), SH2(wb_, 1), p_); \
  p_ = dot2f(SH2(hb_, 2), SH2(wb_, 2), p_); \
  p_ = dot2f(SH2(hb_, 3), SH2(wb_, 3), p_); \
  part2[kq_][u2_] = p_; }

#define MLPRED(dst) { \
  int v_ = t - 960; \
  float hv_ = part2[0][v_]+part2[1][v_]+part2[2][v_]+part2[3][v_] \
            + part2[4][v_]+part2[5][v_]+part2[6][v_]+part2[7][v_] \
            + part2[8][v_]+part2[9][v_]+part2[10][v_]+part2[11][v_] \
            + part2[12][v_]+part2[13][v_]+part2[14][v_]+part2[15][v_] + s_bs1[v_]; \
  hv_ = fmaxf(hv_, 0.f); \
  float c2_ = hv_ * s_ws2[v_]; \
  for (int off_ = 32; off_ > 0; off_ >>= 1) c2_ += __shfl_down(c2_, off_); \
  if (v_ == 0) dst = 1.f / (1.f + expf(-(c2_ + s_bs2))); }

__global__ __launch_bounds__(1024) void rnn_kernel(
    const float* __restrict__ z,
    const float* __restrict__ nf,
    const float* __restrict__ bs1,
    const float* __restrict__ Ws2,
    const float* __restrict__ bs2,
    float* __restrict__ ws) {
  __shared__ __align__(16) __half s_wl[32768];   // 64 KB LDS weight zone
  __shared__ __align__(16) __half s_a2[5376];
  __shared__ __align__(16) __half s_b2[5376];
  __shared__ __align__(16) __half s_ws1[16384];
  __shared__ __align__(16) __half s_gbi[768];
  __shared__ __align__(16) __half s_gbh[768];
  __shared__ __align__(16) float s_hb[256];
  __shared__ __align__(16) float nh[256];
  __shared__ __align__(16) __half nh2[256];
  __shared__ __align__(16) float gh2[256];
  __shared__ __align__(16) __half gh2h[256];
  __shared__ __align__(16) float part[4][1024];
  __shared__ __align__(16) float part2[16][64];
  __shared__ float s_bs1[64], s_ws2[64];
  __shared__ int cls[NN];
  __shared__ float s_bs2;

  const int b = blockIdx.x, t = threadIdx.x;
  const __half* hws = (const __half*)ws;
  float* probs = ws + F_PROBS + (size_t)b * TT;

  // ---- stage LDS ----
  {
    f16x8* dst = (f16x8*)s_wl;
    const f16x8* src = (const f16x8*)(hws + H_WLDS);
    for (int x = t; x < 4096; x += 1024) dst[x] = src[x];
  }
  for (int x = t; x < 5376; x += 1024) {
    s_a2[x] = hws[H_AB + x];
    s_b2[x] = hws[H_AB + 5376 + x];
  }
  for (int x = t; x < 16384; x += 1024) s_ws1[x] = hws[H_WS1 + x];
  if (t < 768) {
    s_gbi[t] = hws[H_GB + t];
    s_gbh[t] = hws[H_GB + 768 + t];
  }
  if (t < 256) {
    s_hb[t] = ws[F_HB + t];
    float v = z[b * 256 + t];
    nh[t] = v; gh2[t] = v;
    __half vh = __float2half(v);
    nh2[t] = vh; gh2h[t] = vh;
  }
  if (t < 64) { s_bs1[t] = bs1[t]; s_ws2[t] = Ws2[t]; }
  if (t == 0) s_bs2 = bs2[0];
  if (t < NN) {
    const float* row = nf + (b * NN + t) * FF;
    int c = 0;
#pragma unroll
    for (int q = 1; q < FF; ++q)
      if (row[q] > 0.5f) c = q;
    cls[t] = c;
  }

  const int kp = t >> 8;      // k-partition (wave-uniform)
  const int oc = t & 255;     // output column; outputs oc+256q

  // ---- node weights: 12 resident f16x8 (48 VGPR), keep-alive enforced ----
  const f16x8* wreg = (const f16x8*)(hws + H_WREG) + (kp * 12) * 256 + oc;
  f16x8 W0 = wreg[0 * 256],  W1 = wreg[1 * 256],  W2 = wreg[2 * 256];
  f16x8 W3 = wreg[3 * 256],  W4 = wreg[4 * 256],  W5 = wreg[5 * 256];
  f16x8 W6 = wreg[6 * 256],  W7 = wreg[7 * 256],  W8 = wreg[8 * 256];
  f16x8 W9 = wreg[9 * 256],  W10 = wreg[10 * 256], W11 = wreg[11 * 256];

  const f16x8* stp = (const f16x8*)(hws + H_WSTR) + (kp * 16) * 256 + oc;
  const f16x8* swl = (const f16x8*)s_wl + (kp * 4) * 256 + oc;
  const f16x8* hv8 = (const f16x8*)nh2 + (kp << 3);
  __syncthreads();

  int base = 0;
  for (int i = 0; i < NN - 1; ++i) {
    const __half* ArH = s_a2 + cls[i] * 768;

    for (int j = i + 1; j < NN; ++j) {
      const __half* BrH = s_b2 + cls[j] * 768;
      const bool pend = (j > i + 1);
      // force W0..W11 to stay in VGPRs across the loop (no rematerialization)
      asm volatile("" : "+v"(W0), "+v"(W1), "+v"(W2), "+v"(W3), "+v"(W4),
                        "+v"(W5), "+v"(W6), "+v"(W7), "+v"(W8), "+v"(W9),
                        "+v"(W10), "+v"(W11));
      // ====== Phase A ======
      float s0 = 0.f, s1 = 0.f, s2 = 0.f, s3 = 0.f;
      // stream group 1 (issue early)
      f16x8 S0 = stp[0 * 256], S1 = stp[1 * 256], S2 = stp[2 * 256], S3 = stp[3 * 256];
      f16x8 S4 = stp[4 * 256], S5 = stp[5 * 256], S6 = stp[6 * 256], S7 = stp[7 * 256];
      // register zone: k-local [0,24), h pairs H0..H2
      f16x8 H0 = hv8[0], H1 = hv8[1], H2 = hv8[2];
      PAIR(W0, H0, 0) PAIR(W1, H0, 1) PAIR(W2, H0, 2) PAIR(W3, H0, 3)
      PAIR(W4, H1, 0) PAIR(W5, H1, 1) PAIR(W6, H1, 2) PAIR(W7, H1, 3)
      PAIR(W8, H2, 0) PAIR(W9, H2, 1) PAIR(W10, H2, 2) PAIR(W11, H2, 3)
      // stream group 2
      f16x8 S8 = stp[8 * 256], S9 = stp[9 * 256], S10 = stp[10 * 256], S11 = stp[11 * 256];
      f16x8 S12 = stp[12 * 256], S13 = stp[13 * 256], S14 = stp[14 * 256], S15 = stp[15 * 256];
      // LDS zone: k-local [24,32)
      {
        f16x8 H3 = hv8[3];
        f16x8 L0 = swl[0 * 256], L1 = swl[1 * 256], L2 = swl[2 * 256], L3 = swl[3 * 256];
        PAIR(L0, H3, 0) PAIR(L1, H3, 1) PAIR(L2, H3, 2) PAIR(L3, H3, 3)
      }
      // stream zone: k-local [32,64)
      {
        f16x8 H4 = hv8[4], H5 = hv8[5], H6 = hv8[6], H7 = hv8[7];
        PAIR(S0, H4, 0) PAIR(S1, H4, 1) PAIR(S2, H4, 2) PAIR(S3, H4, 3)
        PAIR(S4, H5, 0) PAIR(S5, H5, 1) PAIR(S6, H5, 2) PAIR(S7, H5, 3)
        PAIR(S8, H6, 0) PAIR(S9, H6, 1) PAIR(S10, H6, 2) PAIR(S11, H6, 3)
        PAIR(S12, H7, 0) PAIR(S13, H7, 1) PAIR(S14, H7, 2) PAIR(S15, H7, 3)
      }
      part[kp][oc] = s0;
      part[kp][oc + 256] = s1;
      part[kp][oc + 512] = s2;
      part[kp][oc + 768] = s3;
      if (pend) MLPPART()
      __syncthreads();
      // ====== Phase B ======
      if (t < 256) {
        const int u = t;
        float pr  = part[0][u]       + part[1][u]       + part[2][u]       + part[3][u];
        float pz  = part[0][256 + u] + part[1][256 + u] + part[2][256 + u] + part[3][256 + u];
        float pin = part[0][512 + u] + part[1][512 + u] + part[2][512 + u] + part[3][512 + u];
        float phn = part[0][768 + u] + part[1][768 + u] + part[2][768 + u] + part[3][768 + u];
        float ar = (float)ArH[u]       + (float)BrH[u];
        float az = (float)ArH[256 + u] + (float)BrH[256 + u];
        float an = (float)ArH[512 + u] + (float)BrH[512 + u];
        float r  = 1.f / (1.f + expf(-(pr + ar)));
        float zg = 1.f / (1.f + expf(-(pz + az)));
        float n2 = tanhf(pin + an + r * (phn + s_hb[u]));
        float nv = (1.f - zg) * n2 + zg * nh[u];
        nh[u] = nv;
        nh2[u] = __float2half(nv);
      } else if (pend && t >= 960) {
        MLPRED(probs[base + j - i - 2])
      }
      __syncthreads();
    }

    // ====== Graph GRU step (f16 weights streamed, dot2) ======
    {
      if (t < 768) {
        const __half* hsrc2 = (t < 384) ? nh2 : gh2h;   // wave-uniform
        const f16x8* hg = (const f16x8*)hsrc2;
        const f16x4* wg = (const f16x4*)(hws + H_WTG) + t;
        float g0 = 0.f, g1 = 0.f;
#pragma unroll 8
        for (int c = 0; c < 32; ++c) {
          f16x8 Hc = hg[c];
          f16x4 a0 = wg[(c * 4 + 0) * 768];
          f16x4 a1 = wg[(c * 4 + 1) * 768];
          f16x4 a2 = wg[(c * 4 + 2) * 768];
          f16x4 a3 = wg[(c * 4 + 3) * 768];
          g0 = dot2f(SH2(Hc, 0), SH01(a0), g0); g1 = dot2f(SH2(Hc, 0), SH23(a0), g1);
          g0 = dot2f(SH2(Hc, 1), SH01(a1), g0); g1 = dot2f(SH2(Hc, 1), SH23(a1), g1);
          g0 = dot2f(SH2(Hc, 2), SH01(a2), g0); g1 = dot2f(SH2(Hc, 2), SH23(a2), g1);
          g0 = dot2f(SH2(Hc, 3), SH01(a3), g0); g1 = dot2f(SH2(Hc, 3), SH23(a3), g1);
        }
        ((float*)part)[(t << 1)] = g0;
        ((float*)part)[(t << 1) + 1] = g1;
      }
      MLPPART()                   // MLP hidden-part for prob (i, NN-1)
      __syncthreads();
      if (t < 256) {
        const int u = t;
        const float* pf = (const float*)part;
        float gir = pf[u]        + (float)s_gbi[u];
        float giz = pf[256 + u]  + (float)s_gbi[256 + u];
        float gin = pf[512 + u]  + (float)s_gbi[512 + u];
        float ghr = pf[768 + u]  + (float)s_gbh[u];
        float ghz = pf[1024 + u] + (float)s_gbh[256 + u];
        float ghn = pf[1280 + u] + (float)s_gbh[512 + u];
        float r  = 1.f / (1.f + expf(-(gir + ghr)));
        float zg = 1.f / (1.f + expf(-(giz + ghz)));
        float n2 = tanhf(gin + r * ghn);
        float nv = (1.f - zg) * n2 + zg * gh2[u];
        gh2[u] = nv; nh[u] = nv;
        __half vh = __float2half(nv);
        gh2h[u] = vh; nh2[u] = vh;
      } else if (t >= 960) {
        MLPRED(probs[base + NN - 2 - i])
      }
      __syncthreads();
    }
    base += NN - 1 - i;
  }
}

// ContinuousBernoulli icdf + anti-diagonal scatter into adj
__global__ void edges_kernel(const float* __restrict__ u,
                             const float* __restrict__ ws,
                             float* __restrict__ adj) {
  int idx = blockIdx.x * blockDim.x + threadIdx.x;
  if (idx >= BB * TT) return;
  int b = idx / TT, t = idx % TT;
  float prob = ws[F_PROBS + (size_t)b * TT + t];
  float uu = u[idx];
  const float EPSF = 1.1920929e-07f;
  float p = fminf(fmaxf(prob, EPSF), 1.0f - EPSF);
  bool outside = (p < 0.499f) || (p > 0.501f);
  float cut = outside ? p : 0.499f;
  float stable = (log1pf(fmaf(uu, 2.f * cut - 1.f, -cut)) - log1pf(-cut)) /
                 (logf(cut) - log1pf(-cut));
  float e = outside ? stable : uu;
  int d = (int)((1.0f + sqrtf(1.0f + 8.0f * (float)t)) * 0.5f);
  while (d * (d + 1) / 2 <= t) ++d;
  while (d * (d - 1) / 2 > t) --d;
  int k = t - d * (d - 1) / 2;
  int r = k, c = k + (NN - d);
  adj[((size_t)b * NN + r) * NN + c] = e;
  adj[((size_t)b * NN + c) * NN + r] = e;
}

__global__ void xb_kernel(const float* __restrict__ nf,
                          float* __restrict__ out_x,
                          float* __restrict__ out_batch) {
  int idx = blockIdx.x * blockDim.x + threadIdx.x;
  if (idx < BB * NN * FF) out_x[idx] = nf[idx];
  if (idx < BB * NN) out_batch[idx] = (float)(idx >> 5);
}

extern "C" void kernel_launch(void* const* d_in, const int* in_sizes, int n_in,
                              void* d_out, int out_size, void* d_ws, size_t ws_size,
                              hipStream_t stream) {
  const float* z         = (const float*)d_in[0];
  const float* nf        = (const float*)d_in[1];
  const float* u         = (const float*)d_in[2];
  const float* Wih_node  = (const float*)d_in[3];
  const float* Whh_node  = (const float*)d_in[4];
  const float* bih_node  = (const float*)d_in[5];
  const float* bhh_node  = (const float*)d_in[6];
  const float* Wih_graph = (const float*)d_in[7];
  const float* Whh_graph = (const float*)d_in[8];
  const float* bih_graph = (const float*)d_in[9];
  const float* bhh_graph = (const float*)d_in[10];
  const float* Ws1       = (const float*)d_in[11];
  const float* bs1       = (const float*)d_in[12];
  const float* Ws2       = (const float*)d_in[13];
  const float* bs2       = (const float*)d_in[14];

  float* ws = (float*)d_ws;
  float* out_x   = (float*)d_out;                        // [B*N, F]
  float* out_adj = out_x + BB * NN * FF;                 // [B, N, N]
  float* out_batch = out_x + BB * NN * FF + (size_t)BB * NN * NN;

  hipMemsetAsync(out_adj, 0, (size_t)BB * NN * NN * sizeof(float), stream);
  prep_kernel<<<(PREP_N + 255) / 256, 256, 0, stream>>>(
      Wih_node, Whh_node, bih_node, bhh_node,
      Wih_graph, Whh_graph, bih_graph, bhh_graph, Ws1, ws);
  rnn_kernel<<<BB, 1024, 0, stream>>>(z, nf, bs1, Ws2, bs2, ws);
  xb_kernel<<<(BB * NN * FF + 255) / 256, 256, 0, stream>>>(nf, out_x, out_batch);
  edges_kernel<<<(BB * TT + 255) / 256, 256, 0, stream>>>(u, ws, out_adj);
}